// Round 1
// baseline (2571.738 us; speedup 1.0000x reference)
//
#include <hip/hip_runtime.h>
#include <hip/hip_bf16.h>
#include <math.h>

#define NN 1024
#define KNB 16
#define DD 512
#define HH 8
#define FFD 2048
#define EE (NN*KNB)
#define EPS 1e-6f
#define RS3 0.57735026918962576f  /* 1/sqrt(3) */
#define RS2 0.70710678118654752f  /* 1/sqrt(2) */

__device__ __forceinline__ float wave_sum64(float v) {
#pragma unroll
  for (int m = 32; m > 0; m >>= 1) v += __shfl_xor(v, m, 64);
  return v;
}

// ---------------------------------------------------------------------------
// Big GEMM: OUT[b, o, x] = sum_c W[o,c] * IN[b, c, x]  (+ optional tv add for msg)
// O_TILE=128, B_TILE=32, K_TILE=32. 256 threads = 16 (ti, owns 8 o) x 16 (tj, owns cols tj & tj+16)
// ---------------------------------------------------------------------------
__global__ __launch_bounds__(256) void gemm_big(
    const float* __restrict__ W, const float* __restrict__ IN,
    float* __restrict__ OUT, const float* __restrict__ ADD,
    int C, long in_bstride, long out_bstride)
{
  __shared__ float Wl[32 * 132];
  __shared__ float Il[32 * 100];
  const int t  = threadIdx.x;
  const int tj = t & 15;
  const int ti = t >> 4;
  const int o0 = blockIdx.x * 128;
  const long bb0 = (long)blockIdx.y * 32;

  float acc[8][2][3];
#pragma unroll
  for (int i = 0; i < 8; ++i)
#pragma unroll
    for (int j = 0; j < 2; ++j) { acc[i][j][0] = 0.f; acc[i][j][1] = 0.f; acc[i][j][2] = 0.f; }

  const float* inb = IN + bb0 * in_bstride;
  for (int c0 = 0; c0 < C; c0 += 32) {
#pragma unroll
    for (int r = 0; r < 16; ++r) {
      int l = t + 256 * r;
      int o = l >> 5, c = l & 31;
      Wl[c * 132 + o] = W[(long)(o0 + o) * C + c0 + c];
    }
#pragma unroll
    for (int r = 0; r < 12; ++r) {
      int l = t + 256 * r;
      int b = l / 96, rem = l - b * 96;
      Il[b * 100 + rem] = inb[(long)b * in_bstride + (long)c0 * 3 + rem];
    }
    __syncthreads();
#pragma unroll 8
    for (int c = 0; c < 32; ++c) {
      const float4 wa = *(const float4*)(Wl + c * 132 + ti * 8);
      const float4 wb = *(const float4*)(Wl + c * 132 + ti * 8 + 4);
      const float* ip0 = Il + tj * 100 + c * 3;
      const float* ip1 = Il + (tj + 16) * 100 + c * 3;
      float p0x = ip0[0], p0y = ip0[1], p0z = ip0[2];
      float p1x = ip1[0], p1y = ip1[1], p1z = ip1[2];
      float wv[8] = {wa.x, wa.y, wa.z, wa.w, wb.x, wb.y, wb.z, wb.w};
#pragma unroll
      for (int i = 0; i < 8; ++i) {
        acc[i][0][0] += wv[i] * p0x; acc[i][0][1] += wv[i] * p0y; acc[i][0][2] += wv[i] * p0z;
        acc[i][1][0] += wv[i] * p1x; acc[i][1][1] += wv[i] * p1y; acc[i][1][2] += wv[i] * p1z;
      }
    }
    __syncthreads();
  }
#pragma unroll
  for (int j = 0; j < 2; ++j) {
    long b = bb0 + tj + 16 * j;
    const float* addb = ADD ? (ADD + (b >> 4) * 1536) : nullptr;
#pragma unroll
    for (int i = 0; i < 8; ++i) {
      int o = o0 + ti * 8 + i;
      long oa = b * out_bstride + (long)o * 3;
      float r0 = acc[i][j][0], r1 = acc[i][j][1], r2 = acc[i][j][2];
      if (addb) { r0 += addb[o * 3 + 0]; r1 += addb[o * 3 + 1]; r2 += addb[o * 3 + 2]; }
      OUT[oa + 0] = r0; OUT[oa + 1] = r1; OUT[oa + 2] = r2;
    }
  }
}

// ---------------------------------------------------------------------------
// Small GEMM: same math, O_TILE=64, B_TILE=16. h_mode: input slice selected by
// h = o0/64 (for the W_value @ pvagg stage).
// ---------------------------------------------------------------------------
__global__ __launch_bounds__(256) void gemm_small(
    const float* __restrict__ W, const float* __restrict__ IN,
    float* __restrict__ OUT,
    int C, long in_bstride, long out_bstride, int h_mode)
{
  __shared__ float Wl[32 * 68];
  __shared__ float Il[16 * 100];
  const int t  = threadIdx.x;
  const int tj = t & 15;
  const int ti = t >> 4;
  const int o0 = blockIdx.x * 64;
  const long bb0 = (long)blockIdx.y * 16;

  float acc[4][3];
#pragma unroll
  for (int i = 0; i < 4; ++i) { acc[i][0] = 0.f; acc[i][1] = 0.f; acc[i][2] = 0.f; }

  const float* inb = IN + bb0 * in_bstride + (h_mode ? (long)(o0 >> 6) * (long)(C * 3) : 0);
  for (int c0 = 0; c0 < C; c0 += 32) {
#pragma unroll
    for (int r = 0; r < 8; ++r) {
      int l = t + 256 * r;
      int o = l >> 5, c = l & 31;
      Wl[c * 68 + o] = W[(long)(o0 + o) * C + c0 + c];
    }
#pragma unroll
    for (int r = 0; r < 6; ++r) {
      int l = t + 256 * r;
      int b = l / 96, rem = l - b * 96;
      Il[b * 100 + rem] = inb[(long)b * in_bstride + (long)c0 * 3 + rem];
    }
    __syncthreads();
#pragma unroll 8
    for (int c = 0; c < 32; ++c) {
      const float4 wa = *(const float4*)(Wl + c * 68 + ti * 4);
      const float* ip = Il + tj * 100 + c * 3;
      float px = ip[0], py = ip[1], pz = ip[2];
      float wv[4] = {wa.x, wa.y, wa.z, wa.w};
#pragma unroll
      for (int i = 0; i < 4; ++i) {
        acc[i][0] += wv[i] * px; acc[i][1] += wv[i] * py; acc[i][2] += wv[i] * pz;
      }
    }
    __syncthreads();
  }
  long b = bb0 + tj;
#pragma unroll
  for (int i = 0; i < 4; ++i) {
    int o = o0 + ti * 4 + i;
    long oa = b * out_bstride + (long)o * 3;
    OUT[oa + 0] = acc[i][0]; OUT[oa + 1] = acc[i][1]; OUT[oa + 2] = acc[i][2];
  }
}

// ---------------------------------------------------------------------------
// Edge kernel: 4 edges per block (256 thr = 4 waves, one wave per edge).
// MLP(64->32->32->1536) -> w0/w1/w2 in LDS; p_sc; pv (in-place over msg);
// a = p_sc @ W_alpha (LDS-chunked); LN; smooth_lrelu; head-dot -> logits.
// ---------------------------------------------------------------------------
__global__ __launch_bounds__(256) void edge_kernel(
    float* __restrict__ msgpv,
    const float* __restrict__ edge_sh, const float* __restrict__ edge_scalars,
    const float* __restrict__ fc_w1, const float* __restrict__ fc_b1,
    const float* __restrict__ fc_w2, const float* __restrict__ fc_b2,
    const float* __restrict__ fc_w3, const float* __restrict__ fc_b3,
    const float* __restrict__ W_alpha, const float* __restrict__ ln_g,
    const float* __restrict__ ln_b, const float* __restrict__ alpha_dot,
    float* __restrict__ logits)
{
  __shared__ float esl[4][64];
  __shared__ float h1l[4][32];
  __shared__ float h2l[4][32];
  __shared__ float shl[4][4];
  __shared__ float pscl[4][512];
  __shared__ float smem_big[4 * 1536];   // phase C/D: w values; phase E: W_alpha tile

  const int t = threadIdx.x;
  const int e0 = blockIdx.x * 4;

  { // A: stage edge scalars + sh
    int el = t >> 6, i = t & 63;
    esl[el][i] = edge_scalars[(long)(e0 + el) * 64 + i];
  }
  if (t < 16) shl[t >> 2][t & 3] = edge_sh[(long)e0 * 4 + t];
  __syncthreads();

  if (t < 128) { // B1: h1
    int el = t >> 5, j = t & 31;
    float v = fc_b1[j];
#pragma unroll 8
    for (int i = 0; i < 64; ++i) v += esl[el][i] * fc_w1[i * 32 + j];
    h1l[el][j] = v / (1.f + expf(-v));
  }
  __syncthreads();
  if (t < 128) { // B2: h2
    int el = t >> 5, j = t & 31;
    float v = fc_b2[j];
#pragma unroll 8
    for (int i = 0; i < 32; ++i) v += h1l[el][i] * fc_w2[i * 32 + j];
    h2l[el][j] = v / (1.f + expf(-v));
  }
  __syncthreads();

  // C: w = h2 @ fc_w3 + b3 -> smem_big[el][c'] (block-cooperative, each fc_w3 elem read once)
#pragma unroll
  for (int r = 0; r < 24; ++r) {
    int l = t + 256 * r;
    int el2 = l / 1536, cc = l - el2 * 1536;
    float a = fc_b3[cc];
#pragma unroll 8
    for (int j = 0; j < 32; ++j) a += h2l[el2][j] * fc_w3[j * 1536 + cc];
    smem_big[el2 * 1536 + cc] = a;
  }
  __syncthreads();

  const int el = t >> 6, lane = t & 63;
  const long ebase = (long)(e0 + el) * 1536;
  const float s  = shl[el][0], vx = shl[el][1], vy = shl[el][2], vz = shl[el][3];
  const float* wle = smem_big + el * 1536;

  // D: p_sc and pv (in-place over msg)
#pragma unroll
  for (int i = 0; i < 8; ++i) {
    int c = lane + 64 * i;
    float m0 = msgpv[ebase + c * 3 + 0];
    float m1 = msgpv[ebase + c * 3 + 1];
    float m2 = msgpv[ebase + c * 3 + 2];
    float w0 = wle[c], w1 = wle[512 + c], w2 = wle[1024 + c];
    float dotv = m0 * vx + m1 * vy + m2 * vz;
    pscl[el][c] = w0 * dotv * RS3;
    float cx = m1 * vz - m2 * vy;
    float cy = m2 * vx - m0 * vz;
    float cz = m0 * vy - m1 * vx;
    float f1 = w1 * s;
    float f2 = w2 * RS2;
    msgpv[ebase + c * 3 + 0] = f1 * m0 + f2 * cx;
    msgpv[ebase + c * 3 + 1] = f1 * m1 + f2 * cy;
    msgpv[ebase + c * 3 + 2] = f1 * m2 + f2 * cz;
  }
  __syncthreads();

  // E: a_pre[m=lane] = sum_c psc[c] * W_alpha[c, m], W_alpha staged in 64-row chunks
  float accm = 0.f;
  for (int ch = 0; ch < 8; ++ch) {
#pragma unroll
    for (int r = 0; r < 16; ++r) {
      int l = t + 256 * r;               // 4096 elems = 64 c x 64 m
      smem_big[l] = W_alpha[(long)(ch * 64) * 64 + l];
    }
    __syncthreads();
#pragma unroll 8
    for (int cl = 0; cl < 64; ++cl)
      accm += pscl[el][ch * 64 + cl] * smem_big[cl * 64 + lane];
    __syncthreads();
  }

  // F: LayerNorm over 64 m (one wave = one edge), smooth_lrelu, head dot
  float s1 = wave_sum64(accm);
  float s2 = wave_sum64(accm * accm);
  float mu  = s1 * (1.f / 64.f);
  float var = s2 * (1.f / 64.f) - mu * mu;
  float aln = (accm - mu) * rsqrtf(var + EPS) * ln_g[lane] + ln_b[lane];
  float act = 0.6f * aln + 0.4f * aln * tanhf(0.5f * aln);
  float p = act * alpha_dot[lane];       // alpha_dot flat [h*8+j] == [lane]
#pragma unroll
  for (int d2 = 4; d2 > 0; d2 >>= 1) p += __shfl_down(p, d2, 8);
  if ((lane & 7) == 0) logits[(long)(e0 + el) * 8 + (lane >> 3)] = p;
}

// ---------------------------------------------------------------------------
// Softmax over k (per n,h) + aggregation: pvagg[n,h,c,x] = sum_k attn[n,k,h]*pv[e,c,x]
// ---------------------------------------------------------------------------
__global__ __launch_bounds__(256) void attn_agg(
    const float* __restrict__ logits, const float* __restrict__ pv,
    float* __restrict__ pvagg)
{
  __shared__ float atl[16][8];
  const int n = blockIdx.x, t = threadIdx.x;
  if (t < 128) {
    int k = t >> 3, h = t & 7;
    atl[k][h] = logits[((long)n * 16 + k) * 8 + h];
  }
  __syncthreads();
  if (t < 8) {
    int h = t;
    float mx = -1e30f;
    for (int k = 0; k < 16; ++k) mx = fmaxf(mx, atl[k][h]);
    float ex[16]; float sm = 0.f;
    for (int k = 0; k < 16; ++k) { ex[k] = expf(atl[k][h] - mx); sm += ex[k]; }
    float inv = 1.f / sm;
    for (int k = 0; k < 16; ++k) atl[k][h] = ex[k] * inv;
  }
  __syncthreads();

  float acc[6][8];
#pragma unroll
  for (int i = 0; i < 6; ++i)
#pragma unroll
    for (int h = 0; h < 8; ++h) acc[i][h] = 0.f;

  const float* pvb = pv + (long)n * 16 * 1536;
  for (int k = 0; k < 16; ++k) {
    float aw[8];
#pragma unroll
    for (int h = 0; h < 8; ++h) aw[h] = atl[k][h];
#pragma unroll
    for (int i = 0; i < 6; ++i) {
      float mval = pvb[k * 1536 + t + 256 * i];
#pragma unroll
      for (int h = 0; h < 8; ++h) acc[i][h] += aw[h] * mval;
    }
  }
  long ob = (long)n * 12288;
#pragma unroll
  for (int h = 0; h < 8; ++h)
#pragma unroll
    for (int i = 0; i < 6; ++i)
      pvagg[ob + h * 1536 + t + 256 * i] = acc[i][h];
}

// ---------------------------------------------------------------------------
// vn_ln: OUT[n,c,:] = (A+B)[n,c,:] / nrm_c * ((nrm_c - mu)/sqrt(var+eps)*g + b)
// ---------------------------------------------------------------------------
__global__ __launch_bounds__(256) void vn_ln_kernel(
    const float* __restrict__ A, const float* __restrict__ Bp,
    const float* __restrict__ g, const float* __restrict__ bb,
    float* __restrict__ OUT)
{
  const int n = blockIdx.x, t = threadIdx.x;
  const long base = (long)n * 1536;
  float xv[2][3], nrm[2];
#pragma unroll
  for (int q = 0; q < 2; ++q) {
    int c = t + 256 * q;
    float ssq = 0.f;
#pragma unroll
    for (int x = 0; x < 3; ++x) {
      float v = A[base + c * 3 + x] + Bp[base + c * 3 + x];
      xv[q][x] = v; ssq += v * v;
    }
    nrm[q] = sqrtf(ssq + EPS);
  }
  float s1 = nrm[0] + nrm[1];
  float s2 = nrm[0] * nrm[0] + nrm[1] * nrm[1];
  s1 = wave_sum64(s1); s2 = wave_sum64(s2);
  __shared__ float red[8];
  int wid = t >> 6;
  if ((t & 63) == 0) { red[wid] = s1; red[4 + wid] = s2; }
  __syncthreads();
  float S1 = red[0] + red[1] + red[2] + red[3];
  float S2 = red[4] + red[5] + red[6] + red[7];
  float mu  = S1 * (1.f / 512.f);
  float var = S2 * (1.f / 512.f) - mu * mu;
  float rstd = rsqrtf(var + EPS);
#pragma unroll
  for (int q = 0; q < 2; ++q) {
    int c = t + 256 * q;
    float ln = (nrm[q] - mu) * rstd * g[c] + bb[c];
    float sc = ln / nrm[q];
#pragma unroll
    for (int x = 0; x < 3; ++x) OUT[base + c * 3 + x] = xv[q][x] * sc;
  }
}

// ---------------------------------------------------------------------------
// Gate: y <- (dot>=0) ? y : y - 0.8*(dot/dnn)*dvec  (one thread per (n,o))
// ---------------------------------------------------------------------------
__global__ __launch_bounds__(256) void gate_kernel(
    float* __restrict__ y, const float* __restrict__ dv)
{
  long idx = (long)blockIdx.x * 256 + threadIdx.x;
  long b = idx * 3;
  float y0 = y[b], y1 = y[b + 1], y2 = y[b + 2];
  float d0 = dv[b], d1 = dv[b + 1], d2 = dv[b + 2];
  float dot = y0 * d0 + y1 * d1 + y2 * d2;
  if (dot < 0.f) {
    float dnn = d0 * d0 + d1 * d1 + d2 * d2 + EPS;
    float coef = 0.8f * dot / dnn;
    y[b]     = y0 - coef * d0;
    y[b + 1] = y1 - coef * d1;
    y[b + 2] = y2 - coef * d2;
  }
}

// ---------------------------------------------------------------------------
extern "C" void kernel_launch(void* const* d_in, const int* in_sizes, int n_in,
                              void* d_out, int out_size, void* d_ws, size_t ws_size,
                              hipStream_t stream)
{
  const float* tgt          = (const float*)d_in[0];
  const float* memory       = (const float*)d_in[1];
  const float* edge_sh      = (const float*)d_in[2];
  const float* edge_scalars = (const float*)d_in[3];
  const float* W_src   = (const float*)d_in[4];
  const float* W_dst   = (const float*)d_in[5];
  const float* fc_w1   = (const float*)d_in[6];
  const float* fc_b1   = (const float*)d_in[7];
  const float* fc_w2   = (const float*)d_in[8];
  const float* fc_b2   = (const float*)d_in[9];
  const float* fc_w3   = (const float*)d_in[10];
  const float* fc_b3   = (const float*)d_in[11];
  const float* W_alpha = (const float*)d_in[12];
  const float* ln_a_g  = (const float*)d_in[13];
  const float* ln_a_b  = (const float*)d_in[14];
  const float* alpha_dot = (const float*)d_in[15];
  const float* W_value = (const float*)d_in[16];
  const float* W_proj  = (const float*)d_in[17];
  const float* n1_g    = (const float*)d_in[18];
  const float* n1_b    = (const float*)d_in[19];
  const float* n2_g    = (const float*)d_in[20];
  const float* n2_b    = (const float*)d_in[21];
  const float* W_ff1   = (const float*)d_in[22];
  const float* W_ffd   = (const float*)d_in[23];
  const float* W_ff2   = (const float*)d_in[24];
  float* out = (float*)d_out;

  float* ws = (float*)d_ws;
  float* tv     = ws;                       // N*1536          = 1,572,864
  float* msgpv  = tv + 1572864;             // E*1536          = 25,165,824
  float* logits = msgpv + 25165824;         // E*8             = 131,072
  float* pvagg  = logits + 131072;          // N*8*1536        = 12,582,912
  float* nb1    = pvagg + 12582912;         // N*1536
  float* nb2    = nb1 + 1572864;            // N*1536
  // overlay into msgpv region after attn_agg consumed pv:
  float* x1   = msgpv;                      // N*1536
  float* ybuf = msgpv + 1572864;            // N*6144
  float* dvec = ybuf + 6291456;             // N*6144

  // 1. tv = W_dst @ tgt
  gemm_small<<<dim3(8, 64), 256, 0, stream>>>(W_dst, tgt, tv, 512, 1536, 1536, 0);
  // 2. msg = W_src @ memory + tv
  gemm_big<<<dim3(4, 512), 256, 0, stream>>>(W_src, memory, msgpv, tv, 512, 1536, 1536);
  // 3. edge fused: MLP, p_sc, pv(in place), logits
  edge_kernel<<<4096, 256, 0, stream>>>(msgpv, edge_sh, edge_scalars,
      fc_w1, fc_b1, fc_w2, fc_b2, fc_w3, fc_b3, W_alpha, ln_a_g, ln_a_b, alpha_dot, logits);
  // 4. softmax + aggregate -> pvagg
  attn_agg<<<1024, 256, 0, stream>>>(logits, msgpv, pvagg);
  // 5. out2 = W_value @ pvagg (h-sliced input)
  gemm_small<<<dim3(8, 64), 256, 0, stream>>>(W_value, pvagg, nb1, 512, 12288, 1536, 1);
  // 6. out3 = W_proj @ out2
  gemm_small<<<dim3(8, 64), 256, 0, stream>>>(W_proj, nb1, nb2, 512, 1536, 1536, 0);
  // 7. x1 = vn_ln(tv + out3)
  vn_ln_kernel<<<1024, 256, 0, stream>>>(tv, nb2, n1_g, n1_b, x1);
  // 8. y = W_ff1 @ x1
  gemm_big<<<dim3(16, 32), 256, 0, stream>>>(W_ff1, x1, ybuf, nullptr, 512, 1536, 6144);
  // 9. dvec = W_ffd @ y
  gemm_big<<<dim3(16, 32), 256, 0, stream>>>(W_ffd, ybuf, dvec, nullptr, 2048, 6144, 6144);
  // 10. gate (in place on y)
  gate_kernel<<<8192, 256, 0, stream>>>(ybuf, dvec);
  // 11. y2 = W_ff2 @ y
  gemm_small<<<dim3(8, 64), 256, 0, stream>>>(W_ff2, ybuf, nb2, 2048, 6144, 1536, 0);
  // 12. out = vn_ln(x1 + y2)
  vn_ln_kernel<<<1024, 256, 0, stream>>>(x1, nb2, n2_g, n2_b, out);
}

// Round 3
// 1070.328 us; speedup vs baseline: 2.4028x; 2.4028x over previous
//
#include <hip/hip_runtime.h>
#include <hip/hip_bf16.h>
#include <math.h>

#define EPS 1e-6f
#define RS3 0.57735026918962576f  /* 1/sqrt(3) */
#define RS2 0.70710678118654752f  /* 1/sqrt(2) */

typedef __attribute__((ext_vector_type(8))) short bf16x8;
typedef __attribute__((ext_vector_type(4))) float f32x4;

__device__ __forceinline__ ushort f2bf(float f) {
  unsigned u = __float_as_uint(f);
  u += 0x7fffu + ((u >> 16) & 1u);      // RNE
  return (ushort)(u >> 16);
}
__device__ __forceinline__ float bf2f(ushort u) {
  return __uint_as_float(((unsigned)u) << 16);
}
__device__ __forceinline__ void split_hl(float v, ushort& h, ushort& l) {
  h = f2bf(v);
  l = f2bf(v - bf2f(h));
}
__device__ __forceinline__ float wave_sum64(float v) {
#pragma unroll
  for (int m = 32; m > 0; m >>= 1) v += __shfl_xor(v, m, 64);
  return v;
}

// ---------------------------------------------------------------------------
// fp32 weights -> bf16 hi/lo (concatenated: W_src|W_dst|W_ff1|W_ffd|W_ff2)
// ---------------------------------------------------------------------------
__global__ __launch_bounds__(256) void cvt_weights_hl(
    const float* __restrict__ w_src, const float* __restrict__ w_dst,
    const float* __restrict__ w_ff1, const float* __restrict__ w_ffd,
    const float* __restrict__ w_ff2, ushort* __restrict__ oh, ushort* __restrict__ ol)
{
  long i = ((long)blockIdx.x * 256 + threadIdx.x) * 8;
  const float* s; long l;
  if      (i < 262144)  { s = w_src; l = i; }
  else if (i < 524288)  { s = w_dst; l = i - 262144; }
  else if (i < 1572864) { s = w_ff1; l = i - 524288; }
  else if (i < 5767168) { s = w_ffd; l = i - 1572864; }
  else                  { s = w_ff2; l = i - 5767168; }
  ushort h[8], lo[8];
#pragma unroll
  for (int j = 0; j < 8; ++j) split_hl(s[l + j], h[j], lo[j]);
  ushort4 h0 = {h[0], h[1], h[2], h[3]}, h1 = {h[4], h[5], h[6], h[7]};
  ushort4 l0 = {lo[0], lo[1], lo[2], lo[3]}, l1 = {lo[4], lo[5], lo[6], lo[7]};
  *(ushort4*)(oh + i) = h0; *(ushort4*)(oh + i + 4) = h1;
  *(ushort4*)(ol + i) = l0; *(ushort4*)(ol + i + 4) = l1;
}

// ---------------------------------------------------------------------------
// fp32 [b][512][3] -> bf16 hi/lo [b][3][512]  (one block per b)
// ---------------------------------------------------------------------------
__global__ __launch_bounds__(256) void cvt_in_hl(
    const float* __restrict__ in, ushort* __restrict__ oh, ushort* __restrict__ ol)
{
  const int b = blockIdx.x, t = threadIdx.x;
  const float* ib = in + (long)b * 1536;
  ushort* obh = oh + (long)b * 1536;
  ushort* obl = ol + (long)b * 1536;
#pragma unroll
  for (int r = 0; r < 6; ++r) {
    int l = t + 256 * r;
    float v = ib[l];
    int c = l / 3, x = l - c * 3;
    ushort h, lo; split_hl(v, h, lo);
    obh[x * 512 + c] = h; obl[x * 512 + c] = lo;
  }
}

// ---------------------------------------------------------------------------
// flat fp32 -> bf16 hi/lo (same layout)
// ---------------------------------------------------------------------------
__global__ __launch_bounds__(256) void cvt_f32_hl(
    const float* __restrict__ in, ushort* __restrict__ oh, ushort* __restrict__ ol)
{
  long i = ((long)blockIdx.x * 256 + threadIdx.x) * 4;
  float4 v = *(const float4*)(in + i);
  ushort h[4], l[4];
  split_hl(v.x, h[0], l[0]); split_hl(v.y, h[1], l[1]);
  split_hl(v.z, h[2], l[2]); split_hl(v.w, h[3], l[3]);
  ushort4 hv = {h[0], h[1], h[2], h[3]}, lv = {l[0], l[1], l[2], l[3]};
  *(ushort4*)(oh + i) = hv;
  *(ushort4*)(ol + i) = lv;
}

// ---------------------------------------------------------------------------
// Wcomb[p][h*512+c] = sum_{o in [64h,64h+64)} W_proj[p][o]*W_value[o][c] -> hi/lo
// ---------------------------------------------------------------------------
__global__ __launch_bounds__(256) void wcomb_kernel(
    const float* __restrict__ Wp, const float* __restrict__ Wv,
    ushort* __restrict__ oh, ushort* __restrict__ ol)
{
  __shared__ float wp[64 * 65];
  __shared__ float wv[64 * 65];
  const int h = blockIdx.x >> 3, ct = blockIdx.x & 7, pt = blockIdx.y;
  const int t = threadIdx.x;
#pragma unroll
  for (int r = 0; r < 16; ++r) {
    int f = r * 256 + t;
    int p = f >> 6, o = f & 63;
    wp[p * 65 + o] = Wp[(long)(pt * 64 + p) * 512 + h * 64 + o];
  }
#pragma unroll
  for (int r = 0; r < 16; ++r) {
    int f = r * 256 + t;
    int o = f >> 6, c = f & 63;
    wv[o * 65 + c] = Wv[(long)(h * 64 + o) * 512 + ct * 64 + c];
  }
  __syncthreads();
  const int tp = t >> 4, tc = t & 15;
  float acc[4][4] = {};
  for (int o = 0; o < 64; ++o) {
    float av[4], bv[4];
#pragma unroll
    for (int i = 0; i < 4; ++i) av[i] = wp[(tp * 4 + i) * 65 + o];
#pragma unroll
    for (int j = 0; j < 4; ++j) bv[j] = wv[o * 65 + tc * 4 + j];
#pragma unroll
    for (int i = 0; i < 4; ++i)
#pragma unroll
      for (int j = 0; j < 4; ++j) acc[i][j] += av[i] * bv[j];
  }
#pragma unroll
  for (int i = 0; i < 4; ++i) {
    int p = pt * 64 + tp * 4 + i;
    ushort h4[4], l4[4];
#pragma unroll
    for (int j = 0; j < 4; ++j) split_hl(acc[i][j], h4[j], l4[j]);
    ushort4 hv = {h4[0], h4[1], h4[2], h4[3]}, lv = {l4[0], l4[1], l4[2], l4[3]};
    long o = (long)p * 4096 + h * 512 + ct * 64 + tc * 4;
    *(ushort4*)(oh + o) = hv;
    *(ushort4*)(ol + o) = lv;
  }
}

// ---------------------------------------------------------------------------
// Split-precision MFMA GEMM: C[j][m] = sum_k A[m][k]*B[j][k]
// A,B given as bf16 hi/lo pairs; product = AhBh + AhBl + AlBh (fp32 acc).
// Tile 128(M) x 96(N), K_TILE=64, 4 waves (2x2), wave tile 64x48.
// B row jj -> element offset (jj/3)*bnp + (jj%3)*K  (bnp = ushort pitch per b).
// outHL=0: fp32 out Cf; outHL=1: hi/lo out CH/CL. ADD (optional, msg-add):
//  += ADD[(jj/48)*1536 + (jj%3)*512 + m]
// ---------------------------------------------------------------------------
__global__ __launch_bounds__(256) void gemm_hl(
    const ushort* __restrict__ AH, const ushort* __restrict__ AL,
    const ushort* __restrict__ BH, const ushort* __restrict__ BL,
    float* __restrict__ Cf, ushort* __restrict__ CH, ushort* __restrict__ CL,
    const float* __restrict__ ADD, int M, int K, long bnp, int outHL)
{
  __shared__ __align__(16) ushort AsH[128 * 72];
  __shared__ __align__(16) ushort AsL[128 * 72];
  __shared__ __align__(16) ushort BsH[96 * 72];
  __shared__ __align__(16) ushort BsL[96 * 72];
  const int t = threadIdx.x;
  const int m0 = blockIdx.x * 128;
  const int j0 = blockIdx.y * 96;
  const int wid = t >> 6, lane = t & 63;
  const int wm = (wid >> 1) * 64, wn = (wid & 1) * 48;
  const int r16 = lane & 15, quad = lane >> 4;

  f32x4 acc[4][3];
#pragma unroll
  for (int i = 0; i < 4; ++i)
#pragma unroll
    for (int j = 0; j < 3; ++j) acc[i][j] = (f32x4){0.f, 0.f, 0.f, 0.f};

  for (int k0 = 0; k0 < K; k0 += 64) {
#pragma unroll
    for (int r = 0; r < 4; ++r) {
      int f = r * 256 + t;
      int m = f >> 3, kc = f & 7;
      long off = (long)(m0 + m) * K + k0 + kc * 8;
      *(uint4*)(AsH + m * 72 + kc * 8) = *(const uint4*)(AH + off);
      *(uint4*)(AsL + m * 72 + kc * 8) = *(const uint4*)(AL + off);
    }
#pragma unroll
    for (int r = 0; r < 3; ++r) {
      int f = r * 256 + t;
      int n = f >> 3, kc = f & 7;
      int jj = j0 + n;
      int bq = jj / 3, xr = jj - bq * 3;
      long off = (long)bq * bnp + (long)xr * K + k0 + kc * 8;
      *(uint4*)(BsH + n * 72 + kc * 8) = *(const uint4*)(BH + off);
      *(uint4*)(BsL + n * 72 + kc * 8) = *(const uint4*)(BL + off);
    }
    __syncthreads();
#pragma unroll
    for (int kh = 0; kh < 2; ++kh) {
      bf16x8 ah[4], al[4], bh[3], bl[3];
#pragma unroll
      for (int i = 0; i < 4; ++i) {
        int ro = (wm + i * 16 + r16) * 72 + kh * 32 + quad * 8;
        ah[i] = *(const bf16x8*)(AsH + ro);
        al[i] = *(const bf16x8*)(AsL + ro);
      }
#pragma unroll
      for (int j = 0; j < 3; ++j) {
        int ro = (wn + j * 16 + r16) * 72 + kh * 32 + quad * 8;
        bh[j] = *(const bf16x8*)(BsH + ro);
        bl[j] = *(const bf16x8*)(BsL + ro);
      }
#pragma unroll
      for (int i = 0; i < 4; ++i)
#pragma unroll
        for (int j = 0; j < 3; ++j) {
          acc[i][j] = __builtin_amdgcn_mfma_f32_16x16x32_bf16(ah[i], bh[j], acc[i][j], 0, 0, 0);
          acc[i][j] = __builtin_amdgcn_mfma_f32_16x16x32_bf16(ah[i], bl[j], acc[i][j], 0, 0, 0);
          acc[i][j] = __builtin_amdgcn_mfma_f32_16x16x32_bf16(al[i], bh[j], acc[i][j], 0, 0, 0);
        }
    }
    __syncthreads();
  }

#pragma unroll
  for (int j = 0; j < 3; ++j) {
    int jj = j0 + wn + j * 16 + r16;           // output row (N dim)
    const float* ap = ADD ? (ADD + (long)(jj / 48) * 1536 + (jj % 3) * 512) : nullptr;
#pragma unroll
    for (int i = 0; i < 4; ++i) {
      int mm = m0 + wm + i * 16 + quad * 4;    // 4 consecutive cols (M dim)
      f32x4 v = acc[i][j];
      if (ap) { v.x += ap[mm]; v.y += ap[mm + 1]; v.z += ap[mm + 2]; v.w += ap[mm + 3]; }
      long o = (long)jj * M + mm;
      if (!outHL) {
        *(f32x4*)(Cf + o) = v;
      } else {
        ushort h[4], l[4];
        split_hl(v.x, h[0], l[0]); split_hl(v.y, h[1], l[1]);
        split_hl(v.z, h[2], l[2]); split_hl(v.w, h[3], l[3]);
        ushort4 hv = {h[0], h[1], h[2], h[3]}, lv = {l[0], l[1], l[2], l[3]};
        *(ushort4*)(CH + o) = hv;
        *(ushort4*)(CL + o) = lv;
      }
    }
  }
}

// ---------------------------------------------------------------------------
// Edge kernel: msg in hi/lo bf16 [e][3][512]; in-place -> pv hi/lo.
// 4 edges/block, 1 wave/edge. All math fp32.
// ---------------------------------------------------------------------------
__global__ __launch_bounds__(256) void edge_kernel(
    ushort* __restrict__ msgH, ushort* __restrict__ msgL,
    const float* __restrict__ edge_sh, const float* __restrict__ edge_scalars,
    const float* __restrict__ fc_w1, const float* __restrict__ fc_b1,
    const float* __restrict__ fc_w2, const float* __restrict__ fc_b2,
    const float* __restrict__ fc_w3, const float* __restrict__ fc_b3,
    const float* __restrict__ W_alpha, const float* __restrict__ ln_g,
    const float* __restrict__ ln_b, const float* __restrict__ alpha_dot,
    float* __restrict__ logits)
{
  __shared__ float esl[4][64];
  __shared__ float h1l[4][32];
  __shared__ float h2l[4][32];
  __shared__ float shl[4][4];
  __shared__ float pscl[4][512];
  __shared__ float smem_big[4 * 1536];

  const int t = threadIdx.x;
  const int e0 = blockIdx.x * 4;

  { int el = t >> 6, i = t & 63;
    esl[el][i] = edge_scalars[(long)(e0 + el) * 64 + i]; }
  if (t < 16) shl[t >> 2][t & 3] = edge_sh[(long)e0 * 4 + t];
  __syncthreads();

  if (t < 128) {
    int el = t >> 5, j = t & 31;
    float v = fc_b1[j];
#pragma unroll 8
    for (int i = 0; i < 64; ++i) v += esl[el][i] * fc_w1[i * 32 + j];
    h1l[el][j] = v / (1.f + expf(-v));
  }
  __syncthreads();
  if (t < 128) {
    int el = t >> 5, j = t & 31;
    float v = fc_b2[j];
#pragma unroll 8
    for (int i = 0; i < 32; ++i) v += h1l[el][i] * fc_w2[i * 32 + j];
    h2l[el][j] = v / (1.f + expf(-v));
  }
  __syncthreads();

#pragma unroll
  for (int r = 0; r < 24; ++r) {
    int l = t + 256 * r;
    int el2 = l / 1536, cc = l - el2 * 1536;
    float a = fc_b3[cc];
#pragma unroll 8
    for (int j = 0; j < 32; ++j) a += h2l[el2][j] * fc_w3[j * 1536 + cc];
    smem_big[el2 * 1536 + cc] = a;
  }
  __syncthreads();

  const int el = t >> 6, lane = t & 63;
  const long ebase = (long)(e0 + el) * 1536;
  const float s  = shl[el][0], vx = shl[el][1], vy = shl[el][2], vz = shl[el][3];
  const float* wle = smem_big + el * 1536;

#pragma unroll
  for (int i = 0; i < 8; ++i) {
    int c = lane + 64 * i;
    float m0 = bf2f(msgH[ebase + c])        + bf2f(msgL[ebase + c]);
    float m1 = bf2f(msgH[ebase + 512 + c])  + bf2f(msgL[ebase + 512 + c]);
    float m2 = bf2f(msgH[ebase + 1024 + c]) + bf2f(msgL[ebase + 1024 + c]);
    float w0 = wle[c], w1 = wle[512 + c], w2 = wle[1024 + c];
    float dotv = m0 * vx + m1 * vy + m2 * vz;
    pscl[el][c] = w0 * dotv * RS3;
    float cx = m1 * vz - m2 * vy;
    float cy = m2 * vx - m0 * vz;
    float cz = m0 * vy - m1 * vx;
    float f1 = w1 * s;
    float f2 = w2 * RS2;
    float p0 = f1 * m0 + f2 * cx;
    float p1 = f1 * m1 + f2 * cy;
    float p2 = f1 * m2 + f2 * cz;
    ushort h, lo;
    split_hl(p0, h, lo); msgH[ebase + c] = h;        msgL[ebase + c] = lo;
    split_hl(p1, h, lo); msgH[ebase + 512 + c] = h;  msgL[ebase + 512 + c] = lo;
    split_hl(p2, h, lo); msgH[ebase + 1024 + c] = h; msgL[ebase + 1024 + c] = lo;
  }
  __syncthreads();

  float accm = 0.f;
  for (int ch = 0; ch < 8; ++ch) {
#pragma unroll
    for (int r = 0; r < 16; ++r) {
      int l = t + 256 * r;
      smem_big[l] = W_alpha[(long)(ch * 64) * 64 + l];
    }
    __syncthreads();
#pragma unroll 8
    for (int cl = 0; cl < 64; ++cl)
      accm += pscl[el][ch * 64 + cl] * smem_big[cl * 64 + lane];
    __syncthreads();
  }

  float s1 = wave_sum64(accm);
  float s2 = wave_sum64(accm * accm);
  float mu  = s1 * (1.f / 64.f);
  float var = s2 * (1.f / 64.f) - mu * mu;
  float aln = (accm - mu) * rsqrtf(var + EPS) * ln_g[lane] + ln_b[lane];
  float act = 0.6f * aln + 0.4f * aln * tanhf(0.5f * aln);
  float p = act * alpha_dot[lane];
#pragma unroll
  for (int d2 = 4; d2 > 0; d2 >>= 1) p += __shfl_down(p, d2, 8);
  if ((lane & 7) == 0) logits[(long)(e0 + el) * 8 + (lane >> 3)] = p;
}

// ---------------------------------------------------------------------------
// Softmax over k + aggregation, IN PLACE: block n reads its pv slice
// (edges 16n..16n+15, hi/lo), writes pvagg[n] hi/lo over the same slice.
// pvagg row (n,x) lives at ushort offset n*24576 + x*4096 (+h*512+c).
// ---------------------------------------------------------------------------
__global__ __launch_bounds__(256) void attn_agg(
    const float* __restrict__ logits, ushort* __restrict__ pvH, ushort* __restrict__ pvL)
{
  __shared__ float atl[16][8];
  const int n = blockIdx.x, t = threadIdx.x;
  if (t < 128) {
    int k = t >> 3, h = t & 7;
    atl[k][h] = logits[((long)n * 16 + k) * 8 + h];
  }
  __syncthreads();
  if (t < 8) {
    int h = t;
    float mx = -1e30f;
    for (int k = 0; k < 16; ++k) mx = fmaxf(mx, atl[k][h]);
    float ex[16]; float sm = 0.f;
    for (int k = 0; k < 16; ++k) { ex[k] = expf(atl[k][h] - mx); sm += ex[k]; }
    float inv = 1.f / sm;
    for (int k = 0; k < 16; ++k) atl[k][h] = ex[k] * inv;
  }
  __syncthreads();

  float acc[6][8];
#pragma unroll
  for (int i = 0; i < 6; ++i)
#pragma unroll
    for (int h = 0; h < 8; ++h) acc[i][h] = 0.f;

  const long sb = (long)n * 24576;
  for (int k = 0; k < 16; ++k) {
    float aw[8];
#pragma unroll
    for (int h = 0; h < 8; ++h) aw[h] = atl[k][h];
#pragma unroll
    for (int i = 0; i < 6; ++i) {
      long off = sb + k * 1536 + t + 256 * i;
      float mval = bf2f(pvH[off]) + bf2f(pvL[off]);
#pragma unroll
      for (int h = 0; h < 8; ++h) acc[i][h] += aw[h] * mval;
    }
  }
  __syncthreads();   // all reads of this block's slice complete before overwrite
#pragma unroll
  for (int i = 0; i < 6; ++i) {
    int l = t + 256 * i;
    int x = l >> 9, c = l & 511;
#pragma unroll
    for (int h = 0; h < 8; ++h) {
      ushort hh, ll; split_hl(acc[i][h], hh, ll);
      long off = sb + x * 4096 + h * 512 + c;
      pvH[off] = hh; pvL[off] = ll;
    }
  }
}

// ---------------------------------------------------------------------------
// vn_ln on xC layout. mode 0: outf fp32 xC + hi/lo xC; mode 1: outf [c*3+x]
// ---------------------------------------------------------------------------
__global__ __launch_bounds__(256) void vn_ln_x(
    const float* __restrict__ A, const float* __restrict__ Bp,
    const float* __restrict__ g, const float* __restrict__ bb,
    float* __restrict__ outf, ushort* __restrict__ outH, ushort* __restrict__ outL,
    int mode)
{
  const int n = blockIdx.x, t = threadIdx.x;
  const long base = (long)n * 1536;
  float xv[2][3], nrm[2];
#pragma unroll
  for (int q = 0; q < 2; ++q) {
    int c = t + 256 * q;
    float ssq = 0.f;
#pragma unroll
    for (int x = 0; x < 3; ++x) {
      float v = A[base + x * 512 + c] + Bp[base + x * 512 + c];
      xv[q][x] = v; ssq += v * v;
    }
    nrm[q] = sqrtf(ssq + EPS);
  }
  float s1 = nrm[0] + nrm[1];
  float s2 = nrm[0] * nrm[0] + nrm[1] * nrm[1];
  s1 = wave_sum64(s1); s2 = wave_sum64(s2);
  __shared__ float red[8];
  int wid = t >> 6;
  if ((t & 63) == 0) { red[wid] = s1; red[4 + wid] = s2; }
  __syncthreads();
  float S1 = red[0] + red[1] + red[2] + red[3];
  float S2 = red[4] + red[5] + red[6] + red[7];
  float mu  = S1 * (1.f / 512.f);
  float var = S2 * (1.f / 512.f) - mu * mu;
  float rstd = rsqrtf(var + EPS);
#pragma unroll
  for (int q = 0; q < 2; ++q) {
    int c = t + 256 * q;
    float ln = (nrm[q] - mu) * rstd * g[c] + bb[c];
    float sc = ln / nrm[q];
    if (mode == 0) {
#pragma unroll
      for (int x = 0; x < 3; ++x) {
        float v = xv[q][x] * sc;
        outf[base + x * 512 + c] = v;
        ushort h, lo; split_hl(v, h, lo);
        outH[base + x * 512 + c] = h;
        outL[base + x * 512 + c] = lo;
      }
    } else {
#pragma unroll
      for (int x = 0; x < 3; ++x)
        outf[base + c * 3 + x] = xv[q][x] * sc;
    }
  }
}

// ---------------------------------------------------------------------------
// Gate on fp32 y, dvec (xC [n][3][2048]) -> gy hi/lo
// ---------------------------------------------------------------------------
__global__ __launch_bounds__(256) void gate_hl(
    const float* __restrict__ y, const float* __restrict__ dv,
    ushort* __restrict__ gh, ushort* __restrict__ gl)
{
  long idx = (long)blockIdx.x * 256 + threadIdx.x;   // over 1024*2048
  long n = idx >> 11; int o = idx & 2047;
  long b = n * 6144 + o;
  float y0 = y[b], y1 = y[b + 2048], y2 = y[b + 4096];
  float d0 = dv[b], d1 = dv[b + 2048], d2 = dv[b + 4096];
  float dot = y0 * d0 + y1 * d1 + y2 * d2;
  if (dot < 0.f) {
    float dnn = d0 * d0 + d1 * d1 + d2 * d2 + EPS;
    float coef = 0.8f * dot / dnn;
    y0 -= coef * d0; y1 -= coef * d1; y2 -= coef * d2;
  }
  ushort h, lo;
  split_hl(y0, h, lo); gh[b] = h;        gl[b] = lo;
  split_hl(y1, h, lo); gh[b + 2048] = h; gl[b + 2048] = lo;
  split_hl(y2, h, lo); gh[b + 4096] = h; gl[b + 4096] = lo;
}

// ---------------------------------------------------------------------------
extern "C" void kernel_launch(void* const* d_in, const int* in_sizes, int n_in,
                              void* d_out, int out_size, void* d_ws, size_t ws_size,
                              hipStream_t stream)
{
  const float* tgt          = (const float*)d_in[0];
  const float* memory       = (const float*)d_in[1];
  const float* edge_sh      = (const float*)d_in[2];
  const float* edge_scalars = (const float*)d_in[3];
  const float* W_src   = (const float*)d_in[4];
  const float* W_dst   = (const float*)d_in[5];
  const float* fc_w1   = (const float*)d_in[6];
  const float* fc_b1   = (const float*)d_in[7];
  const float* fc_w2   = (const float*)d_in[8];
  const float* fc_b2   = (const float*)d_in[9];
  const float* fc_w3   = (const float*)d_in[10];
  const float* fc_b3   = (const float*)d_in[11];
  const float* W_alpha = (const float*)d_in[12];
  const float* ln_a_g  = (const float*)d_in[13];
  const float* ln_a_b  = (const float*)d_in[14];
  const float* alpha_dot = (const float*)d_in[15];
  const float* W_value = (const float*)d_in[16];
  const float* W_proj  = (const float*)d_in[17];
  const float* n1_g    = (const float*)d_in[18];
  const float* n1_b    = (const float*)d_in[19];
  const float* n2_g    = (const float*)d_in[20];
  const float* n2_b    = (const float*)d_in[21];
  const float* W_ff1   = (const float*)d_in[22];
  const float* W_ffd   = (const float*)d_in[23];
  const float* W_ff2   = (const float*)d_in[24];
  float* out = (float*)d_out;

  char* ws = (char*)d_ws;
  // Region A [0, 100663296): msg hi/lo -> (in-place) pv -> pvagg; later FF bufs
  ushort* msgH = (ushort*)(ws + 0);          // 50,331,648 B
  ushort* msgL = (ushort*)(ws + 50331648);   // 50,331,648 B
  float*  yf   = (float*)(ws + 0);           // 25,165,824 B (after pvagg dead)
  ushort* yH   = (ushort*)(ws + 25165824);   // 12,582,912
  ushort* yL   = (ushort*)(ws + 37748736);   // 12,582,912
  float*  dvf  = (float*)(ws + 50331648);    // 25,165,824
  ushort* gyH  = (ushort*)(ws + 75497472);   // 12,582,912
  ushort* gyL  = (ushort*)(ws + 88080384);   // 12,582,912
  // Fixed
  float*  tvx  = (float*)(ws + 100663296);   // 6,291,456
  float*  nb2  = (float*)(ws + 106954752);   // 6,291,456
  // scratch [113246208, 125829120): tgt hi/lo, then mem chunks; later x1
  ushort* tgtH  = (ushort*)(ws + 113246208); // 3,145,728
  ushort* tgtL  = (ushort*)(ws + 116391936); // 3,145,728
  ushort* memcH = (ushort*)(ws + 113246208); // 6,291,456 per chunk
  ushort* memcL = (ushort*)(ws + 119537664); // 6,291,456
  float*  x1f   = (float*)(ws + 113246208);  // 6,291,456
  ushort* x1H   = (ushort*)(ws + 119537664); // 3,145,728
  ushort* x1L   = (ushort*)(ws + 122683392); // 3,145,728
  float*  logits = (float*)(ws + 125829120); // 524,288
  ushort* WH    = (ushort*)(ws + 126353408); // 13,631,488
  ushort* WL    = (ushort*)(ws + 139984896); // 13,631,488
  ushort* wcH   = (ushort*)(ws + 153616384); // 4,194,304
  ushort* wcL   = (ushort*)(ws + 157810688); // 4,194,304  -> peak 162,004,992 B

  // weight segment offsets (ushort elements)
  const long SRC = 0, DST = 262144, FF1 = 524288, FFD = 1572864, FF2 = 5767168;

  // --- prep ---
  cvt_weights_hl<<<3328, 256, 0, stream>>>(W_src, W_dst, W_ff1, W_ffd, W_ff2, WH, WL);
  wcomb_kernel<<<dim3(64, 8), 256, 0, stream>>>(W_proj, W_value, wcH, wcL);

  // 1. tv = W_dst @ tgt  (fp32 out, xC)
  cvt_in_hl<<<1024, 256, 0, stream>>>(tgt, tgtH, tgtL);
  gemm_hl<<<dim3(4, 32), 256, 0, stream>>>(WH + DST, WL + DST, tgtH, tgtL,
      tvx, nullptr, nullptr, nullptr, 512, 512, 1536, 0);

  // 2. msg = W_src @ memory + tv  (hi/lo out), 8 chunks of 2048 edges
  for (int q = 0; q < 8; ++q) {
    cvt_in_hl<<<2048, 256, 0, stream>>>(memory + (long)q * 2048 * 1536, memcH, memcL);
    gemm_hl<<<dim3(4, 64), 256, 0, stream>>>(WH + SRC, WL + SRC, memcH, memcL,
        nullptr, msgH + (long)q * 3145728, msgL + (long)q * 3145728,
        tvx + (long)q * 196608, 512, 512, 1536, 1);
  }

  // 3. edge fused: MLP, p_sc, pv(in place hi/lo), logits
  edge_kernel<<<4096, 256, 0, stream>>>(msgH, msgL, edge_sh, edge_scalars,
      fc_w1, fc_b1, fc_w2, fc_b2, fc_w3, fc_b3, W_alpha, ln_a_g, ln_a_b, alpha_dot, logits);

  // 4. softmax + aggregate -> pvagg hi/lo, in place per-block slice
  attn_agg<<<1024, 256, 0, stream>>>(logits, msgH, msgL);

  // 5. out3 = Wcomb @ pvagg  (fp32); pvagg rows: bnp = 24576
  gemm_hl<<<dim3(4, 32), 256, 0, stream>>>(wcH, wcL, msgH, msgL,
      nb2, nullptr, nullptr, nullptr, 512, 4096, 24576, 0);

  // 6. x1 = vn_ln(tv + out3): fp32 + hi/lo
  vn_ln_x<<<1024, 256, 0, stream>>>(tvx, nb2, n1_g, n1_b, x1f, x1H, x1L, 0);

  // 7. y = W_ff1 @ x1  (fp32 out into region A — pv/pvagg dead)
  gemm_hl<<<dim3(16, 32), 256, 0, stream>>>(WH + FF1, WL + FF1, x1H, x1L,
      yf, nullptr, nullptr, nullptr, 2048, 512, 1536, 0);
  cvt_f32_hl<<<6144, 256, 0, stream>>>(yf, yH, yL);

  // 8. dvec = W_ffd @ y  (fp32)
  gemm_hl<<<dim3(16, 32), 256, 0, stream>>>(WH + FFD, WL + FFD, yH, yL,
      dvf, nullptr, nullptr, nullptr, 2048, 2048, 6144, 0);

  // 9. gate -> gy hi/lo
  gate_hl<<<8192, 256, 0, stream>>>(yf, dvf, gyH, gyL);

  // 10. y2 = W_ff2 @ gy  (fp32, reuse nb2)
  gemm_hl<<<dim3(4, 32), 256, 0, stream>>>(WH + FF2, WL + FF2, gyH, gyL,
      nb2, nullptr, nullptr, nullptr, 512, 2048, 6144, 0);

  // 11. out = vn_ln(x1 + y2) -> interleaved [n][c][3]
  vn_ln_x<<<1024, 256, 0, stream>>>(x1f, nb2, n2_g, n2_b, out, nullptr, nullptr, 1);
}

// Round 4
// 901.133 us; speedup vs baseline: 2.8539x; 1.1878x over previous
//
#include <hip/hip_runtime.h>
#include <hip/hip_bf16.h>
#include <math.h>

#define EPS 1e-6f
#define RS3 0.57735026918962576f  /* 1/sqrt(3) */
#define RS2 0.70710678118654752f  /* 1/sqrt(2) */

typedef __attribute__((ext_vector_type(8))) short bf16x8;
typedef __attribute__((ext_vector_type(4))) float f32x4;

__device__ __forceinline__ ushort f2bf(float f) {
  unsigned u = __float_as_uint(f);
  u += 0x7fffu + ((u >> 16) & 1u);      // RNE
  return (ushort)(u >> 16);
}
__device__ __forceinline__ float bf2f(ushort u) {
  return __uint_as_float(((unsigned)u) << 16);
}
__device__ __forceinline__ void split_hl(float v, ushort& h, ushort& l) {
  h = f2bf(v);
  l = f2bf(v - bf2f(h));
}
__device__ __forceinline__ float wave_sum64(float v) {
#pragma unroll
  for (int m = 32; m > 0; m >>= 1) v += __shfl_xor(v, m, 64);
  return v;
}

// ---------------------------------------------------------------------------
// fp32 weights -> bf16 hi/lo (concatenated: W_src|W_dst|W_ff1|W_ffd|W_ff2)
// ---------------------------------------------------------------------------
__global__ __launch_bounds__(256) void cvt_weights_hl(
    const float* __restrict__ w_src, const float* __restrict__ w_dst,
    const float* __restrict__ w_ff1, const float* __restrict__ w_ffd,
    const float* __restrict__ w_ff2, ushort* __restrict__ oh, ushort* __restrict__ ol)
{
  long i = ((long)blockIdx.x * 256 + threadIdx.x) * 8;
  const float* s; long l;
  if      (i < 262144)  { s = w_src; l = i; }
  else if (i < 524288)  { s = w_dst; l = i - 262144; }
  else if (i < 1572864) { s = w_ff1; l = i - 524288; }
  else if (i < 5767168) { s = w_ffd; l = i - 1572864; }
  else                  { s = w_ff2; l = i - 5767168; }
  ushort h[8], lo[8];
#pragma unroll
  for (int j = 0; j < 8; ++j) split_hl(s[l + j], h[j], lo[j]);
  ushort4 h0 = {h[0], h[1], h[2], h[3]}, h1 = {h[4], h[5], h[6], h[7]};
  ushort4 l0 = {lo[0], lo[1], lo[2], lo[3]}, l1 = {lo[4], lo[5], lo[6], lo[7]};
  *(ushort4*)(oh + i) = h0; *(ushort4*)(oh + i + 4) = h1;
  *(ushort4*)(ol + i) = l0; *(ushort4*)(ol + i + 4) = l1;
}

// ---------------------------------------------------------------------------
// fp32 [b][512][3] -> bf16 hi/lo [b][3][512], 4 b per block, LDS transpose.
// ---------------------------------------------------------------------------
__global__ __launch_bounds__(256) void cvt_in_hl(
    const float* __restrict__ in, ushort* __restrict__ oh, ushort* __restrict__ ol)
{
  __shared__ float lds[6144];
  const int t = threadIdx.x;
  const long b0 = (long)blockIdx.x * 4;
  const float* ib = in + b0 * 1536;
#pragma unroll
  for (int r = 0; r < 6; ++r)
    *(float4*)(lds + r * 1024 + t * 4) = *(const float4*)(ib + r * 1024 + t * 4);
  __syncthreads();
#pragma unroll
  for (int r = 0; r < 24; ++r) {
    int l = t + 256 * r;
    int b = l >> 11, rem = l & 2047;       // 2048? no: per-b 1536 -> use div
    b = l / 1536; rem = l - b * 1536;
    int x = rem >> 9, c = rem & 511;
    float v = lds[b * 1536 + c * 3 + x];
    ushort h, lo; split_hl(v, h, lo);
    oh[(b0 + b) * 1536 + rem] = h;
    ol[(b0 + b) * 1536 + rem] = lo;
  }
}

// ---------------------------------------------------------------------------
// Wcomb[p][h*512+c] = sum_{o in [64h,64h+64)} W_proj[p][o]*W_value[o][c] -> hi/lo
// ---------------------------------------------------------------------------
__global__ __launch_bounds__(256) void wcomb_kernel(
    const float* __restrict__ Wp, const float* __restrict__ Wv,
    ushort* __restrict__ oh, ushort* __restrict__ ol)
{
  __shared__ float wp[64 * 65];
  __shared__ float wv[64 * 65];
  const int h = blockIdx.x >> 3, ct = blockIdx.x & 7, pt = blockIdx.y;
  const int t = threadIdx.x;
#pragma unroll
  for (int r = 0; r < 16; ++r) {
    int f = r * 256 + t;
    int p = f >> 6, o = f & 63;
    wp[p * 65 + o] = Wp[(long)(pt * 64 + p) * 512 + h * 64 + o];
  }
#pragma unroll
  for (int r = 0; r < 16; ++r) {
    int f = r * 256 + t;
    int o = f >> 6, c = f & 63;
    wv[o * 65 + c] = Wv[(long)(h * 64 + o) * 512 + ct * 64 + c];
  }
  __syncthreads();
  const int tp = t >> 4, tc = t & 15;
  float acc[4][4] = {};
  for (int o = 0; o < 64; ++o) {
    float av[4], bv[4];
#pragma unroll
    for (int i = 0; i < 4; ++i) av[i] = wp[(tp * 4 + i) * 65 + o];
#pragma unroll
    for (int j = 0; j < 4; ++j) bv[j] = wv[o * 65 + tc * 4 + j];
#pragma unroll
    for (int i = 0; i < 4; ++i)
#pragma unroll
      for (int j = 0; j < 4; ++j) acc[i][j] += av[i] * bv[j];
  }
#pragma unroll
  for (int i = 0; i < 4; ++i) {
    int p = pt * 64 + tp * 4 + i;
    ushort h4[4], l4[4];
#pragma unroll
    for (int j = 0; j < 4; ++j) split_hl(acc[i][j], h4[j], l4[j]);
    ushort4 hv = {h4[0], h4[1], h4[2], h4[3]}, lv = {l4[0], l4[1], l4[2], l4[3]};
    long o = (long)p * 4096 + h * 512 + ct * 64 + tc * 4;
    *(ushort4*)(oh + o) = hv;
    *(ushort4*)(ol + o) = lv;
  }
}

// ---------------------------------------------------------------------------
// Split-precision MFMA GEMM: C[j][m] = sum_k A[m][k]*B[j][k]
// product = AhBh + AhBl + AlBh (fp32 acc). Template MT: M-tile = 32*MT.
// 4 waves (2x2): wave tile (16*MT) x 48.
// B row jj -> element offset (jj/3)*bnp + (jj%3)*K.
// outmode 0: fp32 Cf; 1: hi/lo CH/CL; 2: both. ADD: += ADD[(jj/48)*1536+(jj%3)*512+m]
// ---------------------------------------------------------------------------
template<int MT>
__global__ __launch_bounds__(256) void gemm_hl(
    const ushort* __restrict__ AH, const ushort* __restrict__ AL,
    const ushort* __restrict__ BH, const ushort* __restrict__ BL,
    float* __restrict__ Cf, ushort* __restrict__ CH, ushort* __restrict__ CL,
    const float* __restrict__ ADD, int M, int K, long bnp, int outmode)
{
  __shared__ __align__(16) ushort AsH[32 * MT * 72];
  __shared__ __align__(16) ushort AsL[32 * MT * 72];
  __shared__ __align__(16) ushort BsH[96 * 72];
  __shared__ __align__(16) ushort BsL[96 * 72];
  const int t = threadIdx.x;
  const int m0 = blockIdx.x * (32 * MT);
  const int j0 = blockIdx.y * 96;
  const int wid = t >> 6, lane = t & 63;
  const int wm = (wid >> 1) * (16 * MT), wn = (wid & 1) * 48;
  const int r16 = lane & 15, quad = lane >> 4;

  f32x4 acc[MT][3];
#pragma unroll
  for (int i = 0; i < MT; ++i)
#pragma unroll
    for (int j = 0; j < 3; ++j) acc[i][j] = (f32x4){0.f, 0.f, 0.f, 0.f};

  for (int k0 = 0; k0 < K; k0 += 64) {
#pragma unroll
    for (int r = 0; r < MT; ++r) {
      int f = r * 256 + t;
      int m = f >> 3, kc = f & 7;
      long off = (long)(m0 + m) * K + k0 + kc * 8;
      *(uint4*)(AsH + m * 72 + kc * 8) = *(const uint4*)(AH + off);
      *(uint4*)(AsL + m * 72 + kc * 8) = *(const uint4*)(AL + off);
    }
#pragma unroll
    for (int r = 0; r < 3; ++r) {
      int f = r * 256 + t;
      int n = f >> 3, kc = f & 7;
      int jj = j0 + n;
      int bq = jj / 3, xr = jj - bq * 3;
      long off = (long)bq * bnp + (long)xr * K + k0 + kc * 8;
      *(uint4*)(BsH + n * 72 + kc * 8) = *(const uint4*)(BH + off);
      *(uint4*)(BsL + n * 72 + kc * 8) = *(const uint4*)(BL + off);
    }
    __syncthreads();
#pragma unroll
    for (int kh = 0; kh < 2; ++kh) {
      bf16x8 ah[MT], al[MT], bh[3], bl[3];
#pragma unroll
      for (int i = 0; i < MT; ++i) {
        int ro = (wm + i * 16 + r16) * 72 + kh * 32 + quad * 8;
        ah[i] = *(const bf16x8*)(AsH + ro);
        al[i] = *(const bf16x8*)(AsL + ro);
      }
#pragma unroll
      for (int j = 0; j < 3; ++j) {
        int ro = (wn + j * 16 + r16) * 72 + kh * 32 + quad * 8;
        bh[j] = *(const bf16x8*)(BsH + ro);
        bl[j] = *(const bf16x8*)(BsL + ro);
      }
#pragma unroll
      for (int i = 0; i < MT; ++i)
#pragma unroll
        for (int j = 0; j < 3; ++j) {
          acc[i][j] = __builtin_amdgcn_mfma_f32_16x16x32_bf16(ah[i], bh[j], acc[i][j], 0, 0, 0);
          acc[i][j] = __builtin_amdgcn_mfma_f32_16x16x32_bf16(ah[i], bl[j], acc[i][j], 0, 0, 0);
          acc[i][j] = __builtin_amdgcn_mfma_f32_16x16x32_bf16(al[i], bh[j], acc[i][j], 0, 0, 0);
        }
    }
    __syncthreads();
  }

#pragma unroll
  for (int j = 0; j < 3; ++j) {
    int jj = j0 + wn + j * 16 + r16;           // output row (N dim)
    const float* ap = ADD ? (ADD + (long)(jj / 48) * 1536 + (jj % 3) * 512) : nullptr;
#pragma unroll
    for (int i = 0; i < MT; ++i) {
      int mm = m0 + wm + i * 16 + quad * 4;    // 4 consecutive cols (M dim)
      f32x4 v = acc[i][j];
      if (ap) { v.x += ap[mm]; v.y += ap[mm + 1]; v.z += ap[mm + 2]; v.w += ap[mm + 3]; }
      long o = (long)jj * M + mm;
      if (outmode != 1) *(f32x4*)(Cf + o) = v;
      if (outmode != 0) {
        ushort h[4], l[4];
        split_hl(v.x, h[0], l[0]); split_hl(v.y, h[1], l[1]);
        split_hl(v.z, h[2], l[2]); split_hl(v.w, h[3], l[3]);
        ushort4 hv = {h[0], h[1], h[2], h[3]}, lv = {l[0], l[1], l[2], l[3]};
        *(ushort4*)(CH + o) = hv;
        *(ushort4*)(CL + o) = lv;
      }
    }
  }
}

// ---------------------------------------------------------------------------
// Edge kernel: msg in hi/lo bf16 [e][3][512]; in-place -> pv hi/lo.
// 4 edges/block, 1 wave/edge. Phase C: fc_w3 read once per block (thread owns
// 6 cc columns x 4 edges). fc_w1/w2/biases staged in LDS (smem_big timeline).
// ---------------------------------------------------------------------------
__global__ __launch_bounds__(256) void edge_kernel(
    ushort* __restrict__ msgH, ushort* __restrict__ msgL,
    const float* __restrict__ edge_sh, const float* __restrict__ edge_scalars,
    const float* __restrict__ fc_w1, const float* __restrict__ fc_b1,
    const float* __restrict__ fc_w2, const float* __restrict__ fc_b2,
    const float* __restrict__ fc_w3, const float* __restrict__ fc_b3,
    const float* __restrict__ W_alpha, const float* __restrict__ ln_g,
    const float* __restrict__ ln_b, const float* __restrict__ alpha_dot,
    float* __restrict__ logits)
{
  __shared__ float esl[4][64];
  __shared__ float h1l[4][32];
  __shared__ float h2l[4][32];
  __shared__ float shl[4][4];
  __shared__ float pscl[4][512];
  __shared__ float smem_big[4 * 1536];   // (a) w1/w2/b stage (b) w values (c) W_alpha tile

  const int t = threadIdx.x;
  const int e0 = blockIdx.x * 4;
  const int W1O = 0, W2O = 2048, B1O = 3072, B2O = 3104;

  { int el = t >> 6, i = t & 63;
    esl[el][i] = edge_scalars[(long)(e0 + el) * 64 + i]; }
  if (t < 16) shl[t >> 2][t & 3] = edge_sh[(long)e0 * 4 + t];
  // stage fc_w1 (2048) | fc_w2 (1024) | fc_b1 (32) | fc_b2 (32)
#pragma unroll
  for (int r = 0; r < 13; ++r) {
    int l = t + 256 * r;
    if (l < 2048)      smem_big[W1O + l] = fc_w1[l];
    else if (l < 3072) smem_big[W2O + (l - 2048)] = fc_w2[l - 2048];
    else if (l < 3104) smem_big[B1O + (l - 3072)] = fc_b1[l - 3072];
    else if (l < 3136) smem_big[B2O + (l - 3104)] = fc_b2[l - 3104];
  }
  __syncthreads();

  if (t < 128) {
    int el = t >> 5, j = t & 31;
    float v = smem_big[B1O + j];
#pragma unroll 8
    for (int i = 0; i < 64; ++i) v += esl[el][i] * smem_big[W1O + i * 32 + j];
    h1l[el][j] = v / (1.f + expf(-v));
  }
  __syncthreads();
  if (t < 128) {
    int el = t >> 5, j = t & 31;
    float v = smem_big[B2O + j];
#pragma unroll 8
    for (int i = 0; i < 32; ++i) v += h1l[el][i] * smem_big[W2O + i * 32 + j];
    h2l[el][j] = v / (1.f + expf(-v));
  }
  __syncthreads();

  // Phase C: w[el][cc] = b3[cc] + sum_j h2[el][j]*fc_w3[j][cc]; fc_w3 read once/block
  {
    float wacc[4][6];
#pragma unroll
    for (int q = 0; q < 6; ++q) {
      float b3 = fc_b3[t + 256 * q];
#pragma unroll
      for (int el = 0; el < 4; ++el) wacc[el][q] = b3;
    }
#pragma unroll 4
    for (int j = 0; j < 32; ++j) {
      float h2e[4];
#pragma unroll
      for (int el = 0; el < 4; ++el) h2e[el] = h2l[el][j];
#pragma unroll
      for (int q = 0; q < 6; ++q) {
        float w3 = fc_w3[j * 1536 + t + 256 * q];
#pragma unroll
        for (int el = 0; el < 4; ++el) wacc[el][q] += h2e[el] * w3;
      }
    }
    __syncthreads();   // phase B consumers of smem_big done before overwrite
#pragma unroll
    for (int q = 0; q < 6; ++q)
#pragma unroll
      for (int el = 0; el < 4; ++el)
        smem_big[el * 1536 + t + 256 * q] = wacc[el][q];
  }
  __syncthreads();

  const int el = t >> 6, lane = t & 63;
  const long ebase = (long)(e0 + el) * 1536;
  const float s  = shl[el][0], vx = shl[el][1], vy = shl[el][2], vz = shl[el][3];
  const float* wle = smem_big + el * 1536;

#pragma unroll
  for (int i = 0; i < 8; ++i) {
    int c = lane + 64 * i;
    float m0 = bf2f(msgH[ebase + c])        + bf2f(msgL[ebase + c]);
    float m1 = bf2f(msgH[ebase + 512 + c])  + bf2f(msgL[ebase + 512 + c]);
    float m2 = bf2f(msgH[ebase + 1024 + c]) + bf2f(msgL[ebase + 1024 + c]);
    float w0 = wle[c], w1 = wle[512 + c], w2 = wle[1024 + c];
    float dotv = m0 * vx + m1 * vy + m2 * vz;
    pscl[el][c] = w0 * dotv * RS3;
    float cx = m1 * vz - m2 * vy;
    float cy = m2 * vx - m0 * vz;
    float cz = m0 * vy - m1 * vx;
    float f1 = w1 * s;
    float f2 = w2 * RS2;
    float p0 = f1 * m0 + f2 * cx;
    float p1 = f1 * m1 + f2 * cy;
    float p2 = f1 * m2 + f2 * cz;
    ushort h, lo;
    split_hl(p0, h, lo); msgH[ebase + c] = h;        msgL[ebase + c] = lo;
    split_hl(p1, h, lo); msgH[ebase + 512 + c] = h;  msgL[ebase + 512 + c] = lo;
    split_hl(p2, h, lo); msgH[ebase + 1024 + c] = h; msgL[ebase + 1024 + c] = lo;
  }
  __syncthreads();

  float accm = 0.f;
  for (int ch = 0; ch < 8; ++ch) {
#pragma unroll
    for (int r = 0; r < 16; ++r) {
      int l = t + 256 * r;
      smem_big[l] = W_alpha[(long)(ch * 64) * 64 + l];
    }
    __syncthreads();
#pragma unroll 8
    for (int cl = 0; cl < 64; ++cl)
      accm += pscl[el][ch * 64 + cl] * smem_big[cl * 64 + lane];
    __syncthreads();
  }

  float s1 = wave_sum64(accm);
  float s2 = wave_sum64(accm * accm);
  float mu  = s1 * (1.f / 64.f);
  float var = s2 * (1.f / 64.f) - mu * mu;
  float aln = (accm - mu) * rsqrtf(var + EPS) * ln_g[lane] + ln_b[lane];
  float act = 0.6f * aln + 0.4f * aln * tanhf(0.5f * aln);
  float p = act * alpha_dot[lane];
#pragma unroll
  for (int d2 = 4; d2 > 0; d2 >>= 1) p += __shfl_down(p, d2, 8);
  if ((lane & 7) == 0) logits[(long)(e0 + el) * 8 + (lane >> 3)] = p;
}

// ---------------------------------------------------------------------------
// Softmax over k + aggregation, IN PLACE per-block slice.
// pvagg row (n,x) at ushort offset n*24576 + x*4096 (+h*512+c).
// ---------------------------------------------------------------------------
__global__ __launch_bounds__(256) void attn_agg(
    const float* __restrict__ logits, ushort* __restrict__ pvH, ushort* __restrict__ pvL)
{
  __shared__ float atl[16][8];
  const int n = blockIdx.x, t = threadIdx.x;
  if (t < 128) {
    int k = t >> 3, h = t & 7;
    atl[k][h] = logits[((long)n * 16 + k) * 8 + h];
  }
  __syncthreads();
  if (t < 8) {
    int h = t;
    float mx = -1e30f;
    for (int k = 0; k < 16; ++k) mx = fmaxf(mx, atl[k][h]);
    float ex[16]; float sm = 0.f;
    for (int k = 0; k < 16; ++k) { ex[k] = expf(atl[k][h] - mx); sm += ex[k]; }
    float inv = 1.f / sm;
    for (int k = 0; k < 16; ++k) atl[k][h] = ex[k] * inv;
  }
  __syncthreads();

  float acc[6][8];
#pragma unroll
  for (int i = 0; i < 6; ++i)
#pragma unroll
    for (int h = 0; h < 8; ++h) acc[i][h] = 0.f;

  const long sb = (long)n * 24576;
  for (int k = 0; k < 16; ++k) {
    float aw[8];
#pragma unroll
    for (int h = 0; h < 8; ++h) aw[h] = atl[k][h];
#pragma unroll
    for (int i = 0; i < 6; ++i) {
      long off = sb + k * 1536 + t + 256 * i;
      float mval = bf2f(pvH[off]) + bf2f(pvL[off]);
#pragma unroll
      for (int h = 0; h < 8; ++h) acc[i][h] += aw[h] * mval;
    }
  }
  __syncthreads();
#pragma unroll
  for (int i = 0; i < 6; ++i) {
    int l = t + 256 * i;
    int x = l >> 9, c = l & 511;
#pragma unroll
    for (int h = 0; h < 8; ++h) {
      ushort hh, ll; split_hl(acc[i][h], hh, ll);
      long off = sb + x * 4096 + h * 512 + c;
      pvH[off] = hh; pvL[off] = ll;
    }
  }
}

// ---------------------------------------------------------------------------
// vn_ln on xC layout. mode 0: outf fp32 xC + hi/lo xC; mode 1: outf [c*3+x]
// ---------------------------------------------------------------------------
__global__ __launch_bounds__(256) void vn_ln_x(
    const float* __restrict__ A, const float* __restrict__ Bp,
    const float* __restrict__ g, const float* __restrict__ bb,
    float* __restrict__ outf, ushort* __restrict__ outH, ushort* __restrict__ outL,
    int mode)
{
  const int n = blockIdx.x, t = threadIdx.x;
  const long base = (long)n * 1536;
  float xv[2][3], nrm[2];
#pragma unroll
  for (int q = 0; q < 2; ++q) {
    int c = t + 256 * q;
    float ssq = 0.f;
#pragma unroll
    for (int x = 0; x < 3; ++x) {
      float v = A[base + x * 512 + c] + Bp[base + x * 512 + c];
      xv[q][x] = v; ssq += v * v;
    }
    nrm[q] = sqrtf(ssq + EPS);
  }
  float s1 = nrm[0] + nrm[1];
  float s2 = nrm[0] * nrm[0] + nrm[1] * nrm[1];
  s1 = wave_sum64(s1); s2 = wave_sum64(s2);
  __shared__ float red[8];
  int wid = t >> 6;
  if ((t & 63) == 0) { red[wid] = s1; red[4 + wid] = s2; }
  __syncthreads();
  float S1 = red[0] + red[1] + red[2] + red[3];
  float S2 = red[4] + red[5] + red[6] + red[7];
  float mu  = S1 * (1.f / 512.f);
  float var = S2 * (1.f / 512.f) - mu * mu;
  float rstd = rsqrtf(var + EPS);
#pragma unroll
  for (int q = 0; q < 2; ++q) {
    int c = t + 256 * q;
    float ln = (nrm[q] - mu) * rstd * g[c] + bb[c];
    float sc = ln / nrm[q];
    if (mode == 0) {
#pragma unroll
      for (int x = 0; x < 3; ++x) {
        float v = xv[q][x] * sc;
        outf[base + x * 512 + c] = v;
        ushort h, lo; split_hl(v, h, lo);
        outH[base + x * 512 + c] = h;
        outL[base + x * 512 + c] = lo;
      }
    } else {
#pragma unroll
      for (int x = 0; x < 3; ++x)
        outf[base + c * 3 + x] = xv[q][x] * sc;
    }
  }
}

// ---------------------------------------------------------------------------
// Gate on fp32 y, dvec (xC [n][3][2048]) -> gy hi/lo
// ---------------------------------------------------------------------------
__global__ __launch_bounds__(256) void gate_hl(
    const float* __restrict__ y, const float* __restrict__ dv,
    ushort* __restrict__ gh, ushort* __restrict__ gl)
{
  long idx = (long)blockIdx.x * 256 + threadIdx.x;   // over 1024*2048
  long n = idx >> 11; int o = idx & 2047;
  long b = n * 6144 + o;
  float y0 = y[b], y1 = y[b + 2048], y2 = y[b + 4096];
  float d0 = dv[b], d1 = dv[b + 2048], d2 = dv[b + 4096];
  float dot = y0 * d0 + y1 * d1 + y2 * d2;
  if (dot < 0.f) {
    float dnn = d0 * d0 + d1 * d1 + d2 * d2 + EPS;
    float coef = 0.8f * dot / dnn;
    y0 -= coef * d0; y1 -= coef * d1; y2 -= coef * d2;
  }
  ushort h, lo;
  split_hl(y0, h, lo); gh[b] = h;        gl[b] = lo;
  split_hl(y1, h, lo); gh[b + 2048] = h; gl[b + 2048] = lo;
  split_hl(y2, h, lo); gh[b + 4096] = h; gl[b + 4096] = lo;
}

// ---------------------------------------------------------------------------
extern "C" void kernel_launch(void* const* d_in, const int* in_sizes, int n_in,
                              void* d_out, int out_size, void* d_ws, size_t ws_size,
                              hipStream_t stream)
{
  const float* tgt          = (const float*)d_in[0];
  const float* memory       = (const float*)d_in[1];
  const float* edge_sh      = (const float*)d_in[2];
  const float* edge_scalars = (const float*)d_in[3];
  const float* W_src   = (const float*)d_in[4];
  const float* W_dst   = (const float*)d_in[5];
  const float* fc_w1   = (const float*)d_in[6];
  const float* fc_b1   = (const float*)d_in[7];
  const float* fc_w2   = (const float*)d_in[8];
  const float* fc_b2   = (const float*)d_in[9];
  const float* fc_w3   = (const float*)d_in[10];
  const float* fc_b3   = (const float*)d_in[11];
  const float* W_alpha = (const float*)d_in[12];
  const float* ln_a_g  = (const float*)d_in[13];
  const float* ln_a_b  = (const float*)d_in[14];
  const float* alpha_dot = (const float*)d_in[15];
  const float* W_value = (const float*)d_in[16];
  const float* W_proj  = (const float*)d_in[17];
  const float* n1_g    = (const float*)d_in[18];
  const float* n1_b    = (const float*)d_in[19];
  const float* n2_g    = (const float*)d_in[20];
  const float* n2_b    = (const float*)d_in[21];
  const float* W_ff1   = (const float*)d_in[22];
  const float* W_ffd   = (const float*)d_in[23];
  const float* W_ff2   = (const float*)d_in[24];
  float* out = (float*)d_out;

  char* ws = (char*)d_ws;
  // Region A [0, 100663296): msg hi/lo -> (in-place) pv -> pvagg; later FF bufs
  ushort* msgH = (ushort*)(ws + 0);          // 50,331,648 B
  ushort* msgL = (ushort*)(ws + 50331648);   // 50,331,648 B
  float*  yf   = (float*)(ws + 0);           // 25,165,824 B (after pvagg dead)
  ushort* yH   = (ushort*)(ws + 25165824);   // 12,582,912
  ushort* yL   = (ushort*)(ws + 37748736);   // 12,582,912
  float*  dvf  = (float*)(ws + 50331648);    // 25,165,824
  ushort* gyH  = (ushort*)(ws + 75497472);   // 12,582,912
  ushort* gyL  = (ushort*)(ws + 88080384);   // 12,582,912
  // Fixed
  float*  tvx  = (float*)(ws + 100663296);   // 6,291,456
  float*  nb2  = (float*)(ws + 106954752);   // 6,291,456
  // scratch [113246208, 125829120): tgt hi/lo, then mem chunks; later x1
  ushort* tgtH  = (ushort*)(ws + 113246208); // 3,145,728
  ushort* tgtL  = (ushort*)(ws + 116391936); // 3,145,728
  ushort* memcH = (ushort*)(ws + 113246208); // 6,291,456 per chunk
  ushort* memcL = (ushort*)(ws + 119537664); // 6,291,456
  float*  x1f   = (float*)(ws + 113246208);  // 6,291,456
  ushort* x1H   = (ushort*)(ws + 119537664); // 3,145,728
  ushort* x1L   = (ushort*)(ws + 122683392); // 3,145,728
  float*  logits = (float*)(ws + 125829120); // 524,288
  ushort* WH    = (ushort*)(ws + 126353408); // 13,631,488
  ushort* WL    = (ushort*)(ws + 139984896); // 13,631,488
  ushort* wcH   = (ushort*)(ws + 153616384); // 4,194,304
  ushort* wcL   = (ushort*)(ws + 157810688); // 4,194,304  -> peak 162,004,992 B

  // weight segment offsets (ushort elements)
  const long SRC = 0, DST = 262144, FF1 = 524288, FFD = 1572864, FF2 = 5767168;

  // --- prep ---
  cvt_weights_hl<<<3328, 256, 0, stream>>>(W_src, W_dst, W_ff1, W_ffd, W_ff2, WH, WL);
  wcomb_kernel<<<dim3(64, 8), 256, 0, stream>>>(W_proj, W_value, wcH, wcL);

  // 1. tv = W_dst @ tgt  (fp32 out, xC)
  cvt_in_hl<<<256, 256, 0, stream>>>(tgt, tgtH, tgtL);
  gemm_hl<2><<<dim3(8, 32), 256, 0, stream>>>(WH + DST, WL + DST, tgtH, tgtL,
      tvx, nullptr, nullptr, nullptr, 512, 512, 1536, 0);

  // 2. msg = W_src @ memory + tv  (hi/lo out), 8 chunks of 2048 edges
  for (int q = 0; q < 8; ++q) {
    cvt_in_hl<<<512, 256, 0, stream>>>(memory + (long)q * 2048 * 1536, memcH, memcL);
    gemm_hl<4><<<dim3(4, 64), 256, 0, stream>>>(WH + SRC, WL + SRC, memcH, memcL,
        nullptr, msgH + (long)q * 3145728, msgL + (long)q * 3145728,
        tvx + (long)q * 196608, 512, 512, 1536, 1);
  }

  // 3. edge fused: MLP, p_sc, pv(in place hi/lo), logits
  edge_kernel<<<4096, 256, 0, stream>>>(msgH, msgL, edge_sh, edge_scalars,
      fc_w1, fc_b1, fc_w2, fc_b2, fc_w3, fc_b3, W_alpha, ln_a_g, ln_a_b, alpha_dot, logits);

  // 4. softmax + aggregate -> pvagg hi/lo, in place per-block slice
  attn_agg<<<1024, 256, 0, stream>>>(logits, msgH, msgL);

  // 5. out3 = Wcomb @ pvagg  (fp32); pvagg rows: bnp = 24576
  gemm_hl<2><<<dim3(8, 32), 256, 0, stream>>>(wcH, wcL, msgH, msgL,
      nb2, nullptr, nullptr, nullptr, 512, 4096, 24576, 0);

  // 6. x1 = vn_ln(tv + out3): fp32 + hi/lo
  vn_ln_x<<<1024, 256, 0, stream>>>(tvx, nb2, n1_g, n1_b, x1f, x1H, x1L, 0);

  // 7. y = W_ff1 @ x1  (fp32 + hi/lo out in one pass; region A dead)
  gemm_hl<4><<<dim3(16, 32), 256, 0, stream>>>(WH + FF1, WL + FF1, x1H, x1L,
      yf, yH, yL, nullptr, 2048, 512, 1536, 2);

  // 8. dvec = W_ffd @ y  (fp32)
  gemm_hl<4><<<dim3(16, 32), 256, 0, stream>>>(WH + FFD, WL + FFD, yH, yL,
      dvf, nullptr, nullptr, nullptr, 2048, 2048, 6144, 0);

  // 9. gate -> gy hi/lo
  gate_hl<<<8192, 256, 0, stream>>>(yf, dvf, gyH, gyL);

  // 10. y2 = W_ff2 @ gy  (fp32, reuse nb2)
  gemm_hl<2><<<dim3(8, 32), 256, 0, stream>>>(WH + FF2, WL + FF2, gyH, gyL,
      nb2, nullptr, nullptr, nullptr, 512, 2048, 6144, 0);

  // 11. out = vn_ln(x1 + y2) -> interleaved [n][c][3]
  vn_ln_x<<<1024, 256, 0, stream>>>(x1f, nb2, n2_g, n2_b, out, nullptr, nullptr, 1);
}